// Round 2
// baseline (841.884 us; speedup 1.0000x reference)
//
#include <hip/hip_runtime.h>

// FootprintExtruder: extrude [H,W] height/seg maps into [Z,H,W] int32 volume.
// Constants from the reference:
#define L1_HEIGHT 0      // z < 0 never true -> branch dead
#define ROOF_HEIGHT 1
#define ROOF_ID_OFFSET 1
#define FP_ID_MIN 100
#define FP_ID_MAX 5000
#define MAX_HEIGHT 384
#define HH 768
#define WW 768
#define HW (HH * WW)     // 589824, divisible by 1024

typedef int vint4 __attribute__((ext_vector_type(4)));  // clang vector: OK for nontemporal builtins

__device__ __forceinline__ int voxel(int z, int hf, int seg) {
    // z < L1_HEIGHT(=0) is impossible; fp_id = (z >= hf-1) ? seg+1 : seg
    bool is_fp = (seg >= FP_ID_MIN) & (seg < FP_ID_MAX);
    int fp = (z >= hf - ROOF_HEIGHT) ? seg + ROOF_ID_OFFSET : seg;
    int v  = is_fp ? fp : seg;
    return (z < hf) ? v : 0;
}

// grid = (HW/1024, MAX_HEIGHT); block = 256; each thread: one int4 (4 elems).
__global__ __launch_bounds__(256) void extrude_kernel(
        const int* __restrict__ hf_map, const int* __restrict__ seg_map,
        int* __restrict__ out) {
    const int p = (blockIdx.x * 256 + threadIdx.x) * 4;  // plane offset
    const int z = blockIdx.y;

    const vint4 hf4 = *(const vint4*)(hf_map  + p);
    const vint4 sg4 = *(const vint4*)(seg_map + p);

    vint4 o;
    o.x = voxel(z, hf4.x, sg4.x);
    o.y = voxel(z, hf4.y, sg4.y);
    o.z = voxel(z, hf4.z, sg4.z);
    o.w = voxel(z, hf4.w, sg4.w);

    // 906 MB write-only stream: nontemporal to avoid L2 pollution.
    __builtin_nontemporal_store(o, (vint4*)(out + (size_t)z * HW + p));
}

extern "C" void kernel_launch(void* const* d_in, const int* in_sizes, int n_in,
                              void* d_out, int out_size, void* d_ws, size_t ws_size,
                              hipStream_t stream) {
    const int* hf  = (const int*)d_in[0];   // height_field [1,768,768] int32
    const int* seg = (const int*)d_in[1];   // seg_map      [1,768,768] int32
    int* out = (int*)d_out;                 // [1,384,768,768] int32

    dim3 grid(HW / 1024, MAX_HEIGHT);       // 576 x 384 blocks
    extrude_kernel<<<grid, 256, 0, stream>>>(hf, seg, out);
}